// Round 8
// baseline (441.232 us; speedup 1.0000x reference)
//
#include <hip/hip_runtime.h>

typedef _Float16 f16;
typedef _Float16 f16x8 __attribute__((ext_vector_type(8)));
typedef float f32x4 __attribute__((ext_vector_type(4)));
typedef float f32x16 __attribute__((ext_vector_type(16)));
typedef int i32x4 __attribute__((ext_vector_type(4)));
typedef unsigned int u32;

#define NN 8192
#define FF 256
#define MASK_NEG -1.0e30f
#define F32X16_ZERO {0.f,0.f,0.f,0.f,0.f,0.f,0.f,0.f,0.f,0.f,0.f,0.f,0.f,0.f,0.f,0.f}

// ---------------- K0: W^T in f16 (so K1 B-frags are contiguous) -------------
__global__ void k0_wt(const float* __restrict__ w, f16* __restrict__ wt) {
    int n = blockIdx.x;
    int k = threadIdx.x;
    wt[n * FF + k] = (f16)w[k * FF + n];
}

// ---------------- K1: h = x @ W  (f16 out) ----------------------------------
__global__ __launch_bounds__(256) void k1_h(const float* __restrict__ x,
                                            const f16* __restrict__ wt,
                                            f16* __restrict__ h) {
    int tid = threadIdx.x;
    int wave = tid >> 6, lane = tid & 63, l15 = lane & 15, lg = lane >> 4;
    int rowBase = blockIdx.x * 32 + (wave & 1) * 16;
    int colBase = (wave >> 1) * 128;

    f16x8 afr[8];
    const float* xr = x + (size_t)(rowBase + l15) * FF + lg * 8;
#pragma unroll
    for (int kk = 0; kk < 8; ++kk) {
        float4 a0 = *(const float4*)(xr + kk * 32);
        float4 a1 = *(const float4*)(xr + kk * 32 + 4);
        f16x8 a;
        a[0] = (f16)a0.x; a[1] = (f16)a0.y; a[2] = (f16)a0.z; a[3] = (f16)a0.w;
        a[4] = (f16)a1.x; a[5] = (f16)a1.y; a[6] = (f16)a1.z; a[7] = (f16)a1.w;
        afr[kk] = a;
    }
#pragma unroll
    for (int cs = 0; cs < 8; ++cs) {
        int col = colBase + cs * 16 + l15;
        f32x4 acc = {0.f, 0.f, 0.f, 0.f};
        const f16* wr = wt + (size_t)col * FF + lg * 8;
#pragma unroll
        for (int kk = 0; kk < 8; ++kk) {
            f16x8 b = *(const f16x8*)(wr + kk * 32);
            acc = __builtin_amdgcn_mfma_f32_16x16x32_f16(afr[kk], b, acc, 0, 0, 0);
        }
#pragma unroll
        for (int r = 0; r < 4; ++r)
            h[(size_t)(rowBase + 4 * lg + r) * FF + col] = (f16)acc[r];
    }
}

// ---------------- K2a: fused adj-pack + partial row-max / row-sumexp --------
// No LDS, no barriers. Wave = 32 rows x 1024 cols via mfma 32x32x16.
// gw = blockIdx*4 + wave; rg = gw>>3 (row group), split = gw&7 (col split).
__global__ __launch_bounds__(256, 2) void k2a(const f16* __restrict__ h,
                                              const int* __restrict__ adj,
                                              u32* __restrict__ maskbits,
                                              float* __restrict__ pm,
                                              float* __restrict__ ps) {
    int tid = threadIdx.x;
    int wave = tid >> 6, lane = tid & 63, l31 = lane & 31, hh = lane >> 5;
    int gw = blockIdx.x * 4 + wave;
    int rowBase = (gw >> 3) * 32;
    int split = gw & 7;
    int c0 = split * 1024;
    int wc0 = c0 >> 5;

    // A-frags register-resident: 32 rows x K=256 (row = l31, k = hh*8 + kk*16)
    f16x8 A[16];
    const f16* ap = h + (size_t)(rowBase + l31) * FF + hh * 8;
#pragma unroll
    for (int kk = 0; kk < 16; ++kk) A[kk] = *(const f16x8*)(ap + kk * 16);

    float m[16], s[16];
#pragma unroll
    for (int r = 0; r < 16; ++r) { m[r] = MASK_NEG; s[r] = 0.f; }

    // adj: this lane packs word (row rowBase+l31, wordcol wc0 + 2b + hh)
    const int* arow = adj + (size_t)(rowBase + l31) * NN;
    i32x4 aj[8];
    {
        const i32x4* ajp = (const i32x4*)(arow + c0 + hh * 32);
#pragma unroll
        for (int k = 0; k < 8; ++k) aj[k] = __builtin_nontemporal_load(ajp + k);
    }

#pragma unroll 1
    for (int b = 0; b < 16; ++b) {
        // pack the word for this batch (loads issued one batch ago)
        u32 word = 0;
#pragma unroll
        for (int k = 0; k < 8; ++k)
#pragma unroll
            for (int c = 0; c < 4; ++c)
                word |= (aj[k][c] > 0 ? 1u : 0u) << (k * 4 + c);
        // persist transposed: mask[wordcol][row] (coalesced 128B/half-wave)
        maskbits[(size_t)(wc0 + 2 * b + hh) * NN + rowBase + l31] = word;

        // prefetch adj for next batch (hidden under MFMA + softmax)
        if (b + 1 < 16) {
            const i32x4* ajp = (const i32x4*)(arow + c0 + (b + 1) * 64 + hh * 32);
#pragma unroll
            for (int k = 0; k < 8; ++k) aj[k] = __builtin_nontemporal_load(ajp + k);
        }

        // e-tile 32 rows x 64 cols: B direct from L2 (col = l31, k = hh*8)
        f32x16 acc0 = F32X16_ZERO, acc1 = F32X16_ZERO;
        const f16* bp = h + (size_t)(c0 + b * 64 + l31) * FF + hh * 8;
#pragma unroll
        for (int kk = 0; kk < 16; ++kk) {
            f16x8 b0 = *(const f16x8*)(bp + kk * 16);
            f16x8 b1 = *(const f16x8*)(bp + 32 * FF + kk * 16);
            acc0 = __builtin_amdgcn_mfma_f32_32x32x16_f16(A[kk], b0, acc0, 0, 0, 0);
            acc1 = __builtin_amdgcn_mfma_f32_32x32x16_f16(A[kk], b1, acc1, 0, 0, 0);
        }

        // online softmax, deferred across the 2 cs-subtiles (same row per reg).
        // bogus accumulation while m==-1e30 is killed by the rescale
        // exp(-1e30 - real) = 0 at the first unmasked value.
#pragma unroll
        for (int r = 0; r < 16; ++r) {
            int R = (r & 3) + 8 * (r >> 2) + 4 * hh;  // C/D row (m74/m101)
            u32 w0 = (u32)__shfl((int)word, R, 64);
            u32 w1 = (u32)__shfl((int)word, R + 32, 64);
            float v0 = ((w0 >> l31) & 1u) ? acc0[r] : MASK_NEG;
            float v1 = ((w1 >> l31) & 1u) ? acc1[r] : MASK_NEG;
            float mn = fmaxf(m[r], fmaxf(v0, v1));
            s[r] = s[r] * __expf(m[r] - mn) + __expf(v0 - mn) + __expf(v1 - mn);
            m[r] = mn;
        }
    }

    // reduce across the 32 lanes of each half (each row's cols live there)
#pragma unroll
    for (int off = 1; off < 32; off <<= 1) {
#pragma unroll
        for (int r = 0; r < 16; ++r) {
            float om = __shfl_xor(m[r], off);
            float os = __shfl_xor(s[r], off);
            float mn = fmaxf(m[r], om);
            s[r] = s[r] * __expf(m[r] - mn) + os * __expf(om - mn);
            m[r] = mn;
        }
    }
    if (l31 == 0) {
#pragma unroll
        for (int r = 0; r < 16; ++r) {
            int row = rowBase + (r & 3) + 8 * (r >> 2) + 4 * hh;
            pm[split * NN + row] = m[r];
            ps[split * NN + row] = s[r];
        }
    }
}

// ---------------- K2r: reduce 8 partials -> C = M + ln(S) -------------------
__global__ void k2r(const float* __restrict__ pm, const float* __restrict__ ps,
                    float* __restrict__ cvec) {
    int row = blockIdx.x * 256 + threadIdx.x;
    float M = MASK_NEG, S = 0.f;
#pragma unroll
    for (int i = 0; i < 8; ++i) {
        float m = pm[i * NN + row];
        float s = ps[i * NN + row];
        float mn = fmaxf(M, m);
        S = S * __expf(M - mn) + s * __expf(m - mn);
        M = mn;
    }
    cvec[row] = M + __logf(S);  // out = exp(v - C)
}

// ---------------- K2b: recompute e, write softmax (no LDS, no barriers) -----
__global__ __launch_bounds__(256, 2) void k2b(const f16* __restrict__ h,
                                              const u32* __restrict__ maskbits,
                                              const float* __restrict__ cvec,
                                              float* __restrict__ out) {
    int tid = threadIdx.x;
    int wave = tid >> 6, lane = tid & 63, l31 = lane & 31, hh = lane >> 5;
    int gw = blockIdx.x * 4 + wave;
    int rowBase = (gw >> 3) * 32;
    int split = gw & 7;
    int c0 = split * 1024;
    int wc0 = c0 >> 5;

    f16x8 A[16];
    const f16* ap = h + (size_t)(rowBase + l31) * FF + hh * 8;
#pragma unroll
    for (int kk = 0; kk < 16; ++kk) A[kk] = *(const f16x8*)(ap + kk * 16);

    float Cv[16];
#pragma unroll
    for (int r = 0; r < 16; ++r)
        Cv[r] = cvec[rowBase + (r & 3) + 8 * (r >> 2) + 4 * hh];

#pragma unroll 1
    for (int b = 0; b < 16; ++b) {
        u32 word = maskbits[(size_t)(wc0 + 2 * b + hh) * NN + rowBase + l31];

        f32x16 acc0 = F32X16_ZERO, acc1 = F32X16_ZERO;
        const f16* bp = h + (size_t)(c0 + b * 64 + l31) * FF + hh * 8;
#pragma unroll
        for (int kk = 0; kk < 16; ++kk) {
            f16x8 b0 = *(const f16x8*)(bp + kk * 16);
            f16x8 b1 = *(const f16x8*)(bp + 32 * FF + kk * 16);
            acc0 = __builtin_amdgcn_mfma_f32_32x32x16_f16(A[kk], b0, acc0, 0, 0, 0);
            acc1 = __builtin_amdgcn_mfma_f32_32x32x16_f16(A[kk], b1, acc1, 0, 0, 0);
        }

#pragma unroll
        for (int r = 0; r < 16; ++r) {
            int R = (r & 3) + 8 * (r >> 2) + 4 * hh;
            u32 w0 = (u32)__shfl((int)word, R, 64);
            u32 w1 = (u32)__shfl((int)word, R + 32, 64);
            float v0 = ((w0 >> l31) & 1u) ? acc0[r] : MASK_NEG;
            float v1 = ((w1 >> l31) & 1u) ? acc1[r] : MASK_NEG;
            // masked: exp(-1e30 - C) underflows to exactly 0 (matches jax)
            size_t o = (size_t)(rowBase + R) * NN + c0 + b * 64 + l31;
            __builtin_nontemporal_store(__expf(v0 - Cv[r]), out + o);
            __builtin_nontemporal_store(__expf(v1 - Cv[r]), out + o + 32);
        }
    }
}

extern "C" void kernel_launch(void* const* d_in, const int* in_sizes, int n_in,
                              void* d_out, int out_size, void* d_ws, size_t ws_size,
                              hipStream_t stream) {
    const float* x   = (const float*)d_in[0];
    const int*   adj = (const int*)d_in[1];
    const float* w   = (const float*)d_in[2];
    float* out = (float*)d_out;
    char* ws = (char*)d_ws;

    // workspace layout (~12.7 MB)
    f16* h    = (f16*)(ws);                                 // 4,194,304 B
    f16* wt   = (f16*)(ws + 4194304);                       //   131,072 B
    u32* mask = (u32*)(ws + 4194304 + 131072);              // 8,388,608 B
    float* pm = (float*)(ws + 4194304 + 131072 + 8388608);  // 8*NN f32
    float* ps = pm + 8 * NN;                                // 8*NN f32
    float* cv = ps + 8 * NN;                                // NN f32

    k0_wt<<<dim3(256), dim3(256), 0, stream>>>(w, wt);
    k1_h <<<dim3(256), dim3(256), 0, stream>>>(x, wt, h);
    k2a  <<<dim3(512), dim3(256), 0, stream>>>(h, adj, mask, pm, ps);
    k2r  <<<dim3(32),  dim3(256), 0, stream>>>(pm, ps, cv);
    k2b  <<<dim3(512), dim3(256), 0, stream>>>(h, mask, cv, out);
}

// Round 11
// 275.506 us; speedup vs baseline: 1.6015x; 1.6015x over previous
//
#include <hip/hip_runtime.h>

typedef _Float16 f16;
typedef _Float16 f16x8 __attribute__((ext_vector_type(8)));
typedef float f32x4 __attribute__((ext_vector_type(4)));
typedef float f32x16 __attribute__((ext_vector_type(16)));
typedef int i32x4 __attribute__((ext_vector_type(4)));
typedef unsigned int u32;

#define NN 8192
#define FF 256
#define MASK_NEG -1.0e30f
#define F32X16_ZERO {0.f,0.f,0.f,0.f,0.f,0.f,0.f,0.f,0.f,0.f,0.f,0.f,0.f,0.f,0.f,0.f}

// async global->LDS, 16B per lane. LDS dest = wave-uniform base + lane*16.
__device__ __forceinline__ void gload_lds16(const void* gsrc, void* ldst) {
    __builtin_amdgcn_global_load_lds(
        (const __attribute__((address_space(1))) u32*)gsrc,
        (__attribute__((address_space(3))) u32*)ldst, 16, 0, 0);
}

// ---------------- K0: W^T in f16 (so K1 B-frags are contiguous) -------------
__global__ void k0_wt(const float* __restrict__ w, f16* __restrict__ wt) {
    int n = blockIdx.x;
    int k = threadIdx.x;
    wt[n * FF + k] = (f16)w[k * FF + n];
}

// ---------------- K1: h = x @ W  (f16 out) ----------------------------------
__global__ __launch_bounds__(256) void k1_h(const float* __restrict__ x,
                                            const f16* __restrict__ wt,
                                            f16* __restrict__ h) {
    int tid = threadIdx.x;
    int wave = tid >> 6, lane = tid & 63, l15 = lane & 15, lg = lane >> 4;
    int rowBase = blockIdx.x * 32 + (wave & 1) * 16;
    int colBase = (wave >> 1) * 128;

    f16x8 afr[8];
    const float* xr = x + (size_t)(rowBase + l15) * FF + lg * 8;
#pragma unroll
    for (int kk = 0; kk < 8; ++kk) {
        float4 a0 = *(const float4*)(xr + kk * 32);
        float4 a1 = *(const float4*)(xr + kk * 32 + 4);
        f16x8 a;
        a[0] = (f16)a0.x; a[1] = (f16)a0.y; a[2] = (f16)a0.z; a[3] = (f16)a0.w;
        a[4] = (f16)a1.x; a[5] = (f16)a1.y; a[6] = (f16)a1.z; a[7] = (f16)a1.w;
        afr[kk] = a;
    }
#pragma unroll
    for (int cs = 0; cs < 8; ++cs) {
        int col = colBase + cs * 16 + l15;
        f32x4 acc = {0.f, 0.f, 0.f, 0.f};
        const f16* wr = wt + (size_t)col * FF + lg * 8;
#pragma unroll
        for (int kk = 0; kk < 8; ++kk) {
            f16x8 b = *(const f16x8*)(wr + kk * 32);
            acc = __builtin_amdgcn_mfma_f32_16x16x32_f16(afr[kk], b, acc, 0, 0, 0);
        }
#pragma unroll
        for (int r = 0; r < 4; ++r)
            h[(size_t)(rowBase + 4 * lg + r) * FF + col] = (f16)acc[r];
    }
}

// ---------------- K2a: fused adj-pack + partial row-max / row-sumexp --------
// grid 512 = 64 row-blocks (128 rows) x 8 col-splits (1024 cols).
// 4 waves = 4 row-groups; per tile: 64-col h-panel (32 KB LDS, single-buffer,
// two barriers per tile -- the replay-stable m97 sync structure).
__global__ __launch_bounds__(256, 2) void k2a(const f16* __restrict__ h,
                                              const int* __restrict__ adj,
                                              u32* __restrict__ maskbits,
                                              float* __restrict__ pm,
                                              float* __restrict__ ps) {
    __shared__ __align__(16) char lds[32768];
    int tid = threadIdx.x;
    int wave = tid >> 6, lane = tid & 63, l31 = lane & 31, hh = lane >> 5;
    int bid = blockIdx.x;
    int rb = bid >> 3, split = bid & 7;
    int rowBase = rb * 128;
    int c0 = split * 1024;

    // A-frags register-resident: 32 rows x K=256 (layout validated r8)
    f16x8 A[16];
    {
        const f16* ap = h + (size_t)(rowBase + wave * 32 + l31) * FF + hh * 8;
#pragma unroll
        for (int kk = 0; kk < 16; ++kk) A[kk] = *(const f16x8*)(ap + kk * 16);
    }
    float m[16], s[16];
#pragma unroll
    for (int r = 0; r < 16; ++r) { m[r] = MASK_NEG; s[r] = 0.f; }

    // this lane packs the word (row rowBase+(tid>>1), wordcol tid&1 of tile)
    int prow = rowBase + (tid >> 1);
    int pwc = tid & 1;
    const int* arow = adj + (size_t)prow * NN + c0 + pwc * 32;
    i32x4 aj[8];
    {
        const i32x4* p = (const i32x4*)arow;
#pragma unroll
        for (int k = 0; k < 8; ++k) aj[k] = __builtin_nontemporal_load(p + k);
    }

#pragma unroll 1
    for (int t = 0; t < 16; ++t) {
        __syncthreads();  // readers of previous panel done
        // stage h[c0+t*64 .. +64) x 256 f16 -> LDS (pre-swizzled source).
        // LDS[c][slot] = h[c][slot ^ (c&31)] in 16B slots.
        {
            const char* hb = (const char*)h + (size_t)(c0 + t * 64) * 512;
#pragma unroll
            for (int i = 0; i < 8; ++i) {
                int sb = i * 256 + wave * 64;   // wave-uniform slot base
                int c = i * 8 + wave * 2 + hh;  // this lane's panel col
                gload_lds16(hb + (size_t)c * 512 + ((l31 ^ (c & 31)) << 4),
                            lds + (size_t)sb * 16);
            }
        }
        __syncthreads();  // vmcnt drain: panel (and last iter's aj) ready

        // pack tile-t word; persist transposed (coalesced per half-wave)
        u32 word = 0;
#pragma unroll
        for (int k = 0; k < 8; ++k)
#pragma unroll
            for (int c = 0; c < 4; ++c)
                word |= (aj[k][c] > 0 ? 1u : 0u) << (k * 4 + c);
        maskbits[(size_t)(split * 32 + t * 2 + pwc) * NN + prow] = word;

        // issue adj loads for t+1 (hidden under GEMM+softmax, drains next bar)
        if (t + 1 < 16) {
            const i32x4* p = (const i32x4*)(arow + (t + 1) * 64);
#pragma unroll
            for (int k = 0; k < 8; ++k) aj[k] = __builtin_nontemporal_load(p + k);
        }

        // GEMM: 32 rows x 64 cols (2 subtiles), B from swizzled LDS
        f32x16 acc0 = F32X16_ZERO, acc1 = F32X16_ZERO;
        const char* base0 = lds + (size_t)l31 * 512;
        const char* base1 = lds + (size_t)(32 + l31) * 512;
        int sw = l31 << 4;
#pragma unroll
        for (int kk = 0; kk < 16; ++kk) {
            int koff = (kk * 32 + hh * 16) ^ sw;
            f16x8 b0 = *(const f16x8*)(base0 + koff);
            f16x8 b1 = *(const f16x8*)(base1 + koff);
            acc0 = __builtin_amdgcn_mfma_f32_32x32x16_f16(A[kk], b0, acc0, 0, 0, 0);
            acc1 = __builtin_amdgcn_mfma_f32_32x32x16_f16(A[kk], b1, acc1, 0, 0, 0);
        }

        // online softmax, one rescale per (r, tile). Bogus accumulation while
        // m==-1e30 is killed by exp(-1e30 - real) = 0 at first unmasked value.
#pragma unroll
        for (int r = 0; r < 16; ++r) {
            int R = (r & 3) + 8 * (r >> 2) + 4 * hh;  // C/D row (validated r8)
            u32 w0 = (u32)__shfl((int)word, R * 2, 64);      // cols +0..31
            u32 w1 = (u32)__shfl((int)word, R * 2 + 1, 64);  // cols +32..63
            float v0 = ((w0 >> l31) & 1u) ? acc0[r] : MASK_NEG;
            float v1 = ((w1 >> l31) & 1u) ? acc1[r] : MASK_NEG;
            float mn = fmaxf(m[r], fmaxf(v0, v1));
            s[r] = s[r] * __expf(m[r] - mn) + __expf(v0 - mn) + __expf(v1 - mn);
            m[r] = mn;
        }
    }

    // reduce across the 32 lanes of each half (disjoint column sets per lane)
#pragma unroll
    for (int off = 1; off < 32; off <<= 1) {
#pragma unroll
        for (int r = 0; r < 16; ++r) {
            float om = __shfl_xor(m[r], off);
            float os = __shfl_xor(s[r], off);
            float mn = fmaxf(m[r], om);
            s[r] = s[r] * __expf(m[r] - mn) + os * __expf(om - mn);
            m[r] = mn;
        }
    }
    if (l31 == 0) {  // lanes 0 and 32 (hh=0/1) write disjoint rows
#pragma unroll
        for (int r = 0; r < 16; ++r) {
            int row = rowBase + wave * 32 + (r & 3) + 8 * (r >> 2) + 4 * hh;
            pm[split * NN + row] = m[r];
            ps[split * NN + row] = s[r];
        }
    }
}

// ---------------- K2r: reduce 8 partials -> C = M + ln(S) -------------------
__global__ void k2r(const float* __restrict__ pm, const float* __restrict__ ps,
                    float* __restrict__ cvec) {
    int row = blockIdx.x * 256 + threadIdx.x;
    float M = MASK_NEG, S = 0.f;
#pragma unroll
    for (int i = 0; i < 8; ++i) {
        float m = pm[i * NN + row];
        float s = ps[i * NN + row];
        float mn = fmaxf(M, m);
        S = S * __expf(M - mn) + s * __expf(m - mn);
        M = mn;
    }
    cvec[row] = M + __logf(S);  // out = exp(v - C)
}

// ---------------- K2b: recompute e, write softmax ---------------------------
// same geometry and sync structure as k2a; writes out (256 MB, nontemporal)
__global__ __launch_bounds__(256, 2) void k2b(const f16* __restrict__ h,
                                              const u32* __restrict__ maskbits,
                                              const float* __restrict__ cvec,
                                              float* __restrict__ out) {
    __shared__ __align__(16) char lds[32768];
    int tid = threadIdx.x;
    int wave = tid >> 6, lane = tid & 63, l31 = lane & 31, hh = lane >> 5;
    int bid = blockIdx.x;
    int rb = bid >> 3, split = bid & 7;
    int rowBase = rb * 128;
    int c0 = split * 1024;

    f16x8 A[16];
    {
        const f16* ap = h + (size_t)(rowBase + wave * 32 + l31) * FF + hh * 8;
#pragma unroll
        for (int kk = 0; kk < 16; ++kk) A[kk] = *(const f16x8*)(ap + kk * 16);
    }
    float Cv[16];
#pragma unroll
    for (int r = 0; r < 16; ++r)
        Cv[r] = cvec[rowBase + wave * 32 + (r & 3) + 8 * (r >> 2) + 4 * hh];

    int prow = rowBase + (tid >> 1);
    int pwc = tid & 1;

#pragma unroll 1
    for (int t = 0; t < 16; ++t) {
        __syncthreads();
        {
            const char* hb = (const char*)h + (size_t)(c0 + t * 64) * 512;
#pragma unroll
            for (int i = 0; i < 8; ++i) {
                int sb = i * 256 + wave * 64;
                int c = i * 8 + wave * 2 + hh;
                gload_lds16(hb + (size_t)c * 512 + ((l31 ^ (c & 31)) << 4),
                            lds + (size_t)sb * 16);
            }
        }
        // this lane's mask word (packed by k2a); drains with the barrier
        u32 word = maskbits[(size_t)(split * 32 + t * 2 + pwc) * NN + prow];
        __syncthreads();

        f32x16 acc0 = F32X16_ZERO, acc1 = F32X16_ZERO;
        const char* base0 = lds + (size_t)l31 * 512;
        const char* base1 = lds + (size_t)(32 + l31) * 512;
        int sw = l31 << 4;
#pragma unroll
        for (int kk = 0; kk < 16; ++kk) {
            int koff = (kk * 32 + hh * 16) ^ sw;
            f16x8 b0 = *(const f16x8*)(base0 + koff);
            f16x8 b1 = *(const f16x8*)(base1 + koff);
            acc0 = __builtin_amdgcn_mfma_f32_32x32x16_f16(A[kk], b0, acc0, 0, 0, 0);
            acc1 = __builtin_amdgcn_mfma_f32_32x32x16_f16(A[kk], b1, acc1, 0, 0, 0);
        }

#pragma unroll
        for (int r = 0; r < 16; ++r) {
            int R = (r & 3) + 8 * (r >> 2) + 4 * hh;
            u32 w0 = (u32)__shfl((int)word, R * 2, 64);
            u32 w1 = (u32)__shfl((int)word, R * 2 + 1, 64);
            float v0 = ((w0 >> l31) & 1u) ? acc0[r] : MASK_NEG;
            float v1 = ((w1 >> l31) & 1u) ? acc1[r] : MASK_NEG;
            // masked: exp(-1e30 - C) underflows to exactly 0 (matches jax)
            size_t o = (size_t)(rowBase + wave * 32 + R) * NN + c0 + t * 64 + l31;
            __builtin_nontemporal_store(__expf(v0 - Cv[r]), out + o);
            __builtin_nontemporal_store(__expf(v1 - Cv[r]), out + o + 32);
        }
    }
}

extern "C" void kernel_launch(void* const* d_in, const int* in_sizes, int n_in,
                              void* d_out, int out_size, void* d_ws, size_t ws_size,
                              hipStream_t stream) {
    const float* x   = (const float*)d_in[0];
    const int*   adj = (const int*)d_in[1];
    const float* w   = (const float*)d_in[2];
    float* out = (float*)d_out;
    char* ws = (char*)d_ws;

    // workspace layout (~13.2 MB)
    f16* h    = (f16*)(ws);                                 // 4,194,304 B
    f16* wt   = (f16*)(ws + 4194304);                       //   131,072 B
    u32* mask = (u32*)(ws + 4194304 + 131072);              // 8,388,608 B
    float* pm = (float*)(ws + 4194304 + 131072 + 8388608);  // 8*NN f32
    float* ps = pm + 8 * NN;                                // 8*NN f32
    float* cv = ps + 8 * NN;                                // NN f32

    k0_wt<<<dim3(256), dim3(256), 0, stream>>>(w, wt);
    k1_h <<<dim3(256), dim3(256), 0, stream>>>(x, wt, h);
    k2a  <<<dim3(512), dim3(256), 0, stream>>>(h, adj, mask, pm, ps);
    k2r  <<<dim3(32),  dim3(256), 0, stream>>>(pm, ps, cv);
    k2b  <<<dim3(512), dim3(256), 0, stream>>>(h, mask, cv, out);
}

// Round 13
// 233.337 us; speedup vs baseline: 1.8910x; 1.1807x over previous
//
#include <hip/hip_runtime.h>

typedef _Float16 f16;
typedef _Float16 f16x8 __attribute__((ext_vector_type(8)));
typedef float f32x4 __attribute__((ext_vector_type(4)));
typedef int i32x4 __attribute__((ext_vector_type(4)));
typedef unsigned int u32;

#define NN 8192
#define FF 256
#define MASK_NEG -1.0e30f

// async global->LDS, 16B per lane. LDS dest = wave-uniform base + lane*16.
__device__ __forceinline__ void gload_lds16(const void* gsrc, void* ldst) {
    __builtin_amdgcn_global_load_lds(
        (const __attribute__((address_space(1))) u32*)gsrc,
        (__attribute__((address_space(3))) u32*)ldst, 16, 0, 0);
}

// ---------------- K0: W^T in f16 (so K1 B-frags are contiguous) -------------
__global__ void k0_wt(const float* __restrict__ w, f16* __restrict__ wt) {
    int n = blockIdx.x;
    int k = threadIdx.x;
    wt[n * FF + k] = (f16)w[k * FF + n];
}

// ---------------- K1: h = x @ W  (f16 out) ----------------------------------
__global__ __launch_bounds__(256) void k1_h(const float* __restrict__ x,
                                            const f16* __restrict__ wt,
                                            f16* __restrict__ h) {
    int tid = threadIdx.x;
    int wave = tid >> 6, lane = tid & 63, l15 = lane & 15, lg = lane >> 4;
    int rowBase = blockIdx.x * 32 + (wave & 1) * 16;
    int colBase = (wave >> 1) * 128;

    f16x8 afr[8];
    const float* xr = x + (size_t)(rowBase + l15) * FF + lg * 8;
#pragma unroll
    for (int kk = 0; kk < 8; ++kk) {
        float4 a0 = *(const float4*)(xr + kk * 32);
        float4 a1 = *(const float4*)(xr + kk * 32 + 4);
        f16x8 a;
        a[0] = (f16)a0.x; a[1] = (f16)a0.y; a[2] = (f16)a0.z; a[3] = (f16)a0.w;
        a[4] = (f16)a1.x; a[5] = (f16)a1.y; a[6] = (f16)a1.z; a[7] = (f16)a1.w;
        afr[kk] = a;
    }
#pragma unroll
    for (int cs = 0; cs < 8; ++cs) {
        int col = colBase + cs * 16 + l15;
        f32x4 acc = {0.f, 0.f, 0.f, 0.f};
        const f16* wr = wt + (size_t)col * FF + lg * 8;
#pragma unroll
        for (int kk = 0; kk < 8; ++kk) {
            f16x8 b = *(const f16x8*)(wr + kk * 32);
            acc = __builtin_amdgcn_mfma_f32_16x16x32_f16(afr[kk], b, acc, 0, 0, 0);
        }
#pragma unroll
        for (int r = 0; r < 4; ++r)
            h[(size_t)(rowBase + 4 * lg + r) * FF + col] = (f16)acc[r];
    }
}

// ---------------- K2a: fused adj-pack + partial row-max / row-sumexp --------
// grid 1024 = 128 row-blocks (64 rows) x 8 col-splits (1024 cols).
// 4 waves x 16 rows; 16 tiles of 64 cols; single 32 KB h-panel, 2 barriers
// per tile (the replay-stable r11 skeleton). adj prefetched in registers.
__global__ __launch_bounds__(256, 4) void k2a(const f16* __restrict__ h,
                                              const int* __restrict__ adj,
                                              u32* __restrict__ maskbits,
                                              float* __restrict__ pm,
                                              float* __restrict__ ps) {
    __shared__ __align__(16) char hbuf[32768];
    int tid = threadIdx.x;
    int wave = tid >> 6, lane = tid & 63, l15 = lane & 15, lg = lane >> 4;
    int bid = blockIdx.x;
    int rb = bid >> 3, split = bid & 7;
    int rowBase = rb * 64;
    int c0 = split * 1024;

    // A-frags: 16 rows x K=256 (16x16x32 layout, validated r5/r6/r7)
    f16x8 A[8];
    {
        const f16* ap = h + (size_t)(rowBase + wave * 16 + l15) * FF + lg * 8;
#pragma unroll
        for (int kk = 0; kk < 8; ++kk) A[kk] = *(const f16x8*)(ap + kk * 32);
    }
    float m[4], s[4];
#pragma unroll
    for (int r = 0; r < 4; ++r) { m[r] = MASK_NEG; s[r] = 0.f; }

    // adj: lane covers row rowBase+wave*16+(lane>>2), col-quarter (lane&3)*16
    int prow = rowBase + wave * 16 + (lane >> 2);
    int q = lane & 3;
    const int* arow = adj + (size_t)prow * NN + c0 + q * 16;
    i32x4 aj[4];
    {
        const i32x4* p = (const i32x4*)arow;
#pragma unroll
        for (int k = 0; k < 4; ++k) aj[k] = __builtin_nontemporal_load(p + k);
    }

#pragma unroll 1
    for (int t = 0; t < 16; ++t) {
        __syncthreads();  // readers of previous panel done
        // stage h[c0+t*64 .. +64) x 256 f16 -> LDS (pre-swizzled source).
        // LDS[c][slot] = h[c][slot ^ (c&31)] in 16B slots.  (r11 verbatim)
        {
            const char* hb = (const char*)h + (size_t)(c0 + t * 64) * 512;
#pragma unroll
            for (int i = 0; i < 8; ++i) {
                int sb = i * 256 + wave * 64;   // wave-uniform slot base
                int c = i * 8 + wave * 2 + (lane >> 5);
                gload_lds16(hb + (size_t)c * 512 + (((lane & 31) ^ (c & 31)) << 4),
                            hbuf + (size_t)sb * 16);
            }
        }
        __syncthreads();  // vmcnt drain: panel (and last iter's aj) ready

        // pack this lane's 16 bits; merge halves so lanes 4*wr+2*w hold
        // the full word for (row wr, word w of tile)
        u32 wp = 0;
#pragma unroll
        for (int k = 0; k < 4; ++k)
#pragma unroll
            for (int c = 0; c < 4; ++c)
                wp |= (aj[k][c] > 0 ? 1u : 0u) << (k * 4 + c);
        wp <<= (q & 1) * 16;
        u32 word = wp | (u32)__shfl_xor((int)wp, 1, 64);
        if ((lane & 1) == 0)
            maskbits[(size_t)(split * 32 + t * 2 + ((lane >> 1) & 1)) * NN
                     + prow] = word;

        // prefetch adj for t+1 (hidden under GEMM+softmax, drains next bar)
        if (t + 1 < 16) {
            const i32x4* p = (const i32x4*)(arow + (t + 1) * 64);
#pragma unroll
            for (int k = 0; k < 4; ++k) aj[k] = __builtin_nontemporal_load(p + k);
        }

        // GEMM: 16 rows x 64 cols (4 subtiles of 16), B from swizzled LDS
        f32x4 acc0 = {0.f, 0.f, 0.f, 0.f}, acc1 = {0.f, 0.f, 0.f, 0.f};
        f32x4 acc2 = {0.f, 0.f, 0.f, 0.f}, acc3 = {0.f, 0.f, 0.f, 0.f};
#pragma unroll
        for (int kk = 0; kk < 8; ++kk) {
            int ks = kk * 4 + lg;  // 16B k-slot within a col's 512B row
            f16x8 b0 = *(const f16x8*)(hbuf + (size_t)l15 * 512
                                       + ((ks ^ l15) << 4));
            f16x8 b1 = *(const f16x8*)(hbuf + (size_t)(16 + l15) * 512
                                       + ((ks ^ (16 + l15)) << 4));
            f16x8 b2 = *(const f16x8*)(hbuf + (size_t)(32 + l15) * 512
                                       + ((ks ^ l15) << 4));
            f16x8 b3 = *(const f16x8*)(hbuf + (size_t)(48 + l15) * 512
                                       + ((ks ^ (16 + l15)) << 4));
            acc0 = __builtin_amdgcn_mfma_f32_16x16x32_f16(A[kk], b0, acc0, 0, 0, 0);
            acc1 = __builtin_amdgcn_mfma_f32_16x16x32_f16(A[kk], b1, acc1, 0, 0, 0);
            acc2 = __builtin_amdgcn_mfma_f32_16x16x32_f16(A[kk], b2, acc2, 0, 0, 0);
            acc3 = __builtin_amdgcn_mfma_f32_16x16x32_f16(A[kk], b3, acc3, 0, 0, 0);
        }

        // online softmax, one rescale per (r, tile). Bogus accumulation while
        // m==-1e30 is killed by exp(-1e30 - real) = 0 at first unmasked value.
#pragma unroll
        for (int r = 0; r < 4; ++r) {
            int R = 4 * lg + r;  // C/D row = 4*(lane>>4)+reg (validated r5/r6)
            u32 wA = (u32)__shfl((int)word, 4 * R, 64);      // word 0: cols 0..31
            u32 wB = (u32)__shfl((int)word, 4 * R + 2, 64);  // word 1: cols 32..63
            float v0 = ((wA >> l15) & 1u) ? acc0[r] : MASK_NEG;
            float v1 = ((wA >> (16 + l15)) & 1u) ? acc1[r] : MASK_NEG;
            float v2 = ((wB >> l15) & 1u) ? acc2[r] : MASK_NEG;
            float v3 = ((wB >> (16 + l15)) & 1u) ? acc3[r] : MASK_NEG;
            float mn = fmaxf(m[r],
                             fmaxf(fmaxf(v0, v1), fmaxf(v2, v3)));
            s[r] = s[r] * __expf(m[r] - mn) + __expf(v0 - mn) + __expf(v1 - mn)
                 + __expf(v2 - mn) + __expf(v3 - mn);
            m[r] = mn;
        }
    }

    // reduce across the 16 l15-lanes (disjoint column sets per lane)
#pragma unroll
    for (int off = 1; off < 16; off <<= 1) {
#pragma unroll
        for (int r = 0; r < 4; ++r) {
            float om = __shfl_xor(m[r], off);
            float os = __shfl_xor(s[r], off);
            float mn = fmaxf(m[r], om);
            s[r] = s[r] * __expf(m[r] - mn) + os * __expf(om - mn);
            m[r] = mn;
        }
    }
    if (l15 == 0) {  // lanes 0,16,32,48 -> lg 0..3 -> rows 4*lg+r
#pragma unroll
        for (int r = 0; r < 4; ++r) {
            int row = rowBase + wave * 16 + 4 * lg + r;
            pm[(size_t)split * NN + row] = m[r];
            ps[(size_t)split * NN + row] = s[r];
        }
    }
}

// ---------------- K2r: reduce 8 partials -> C = M + ln(S) -------------------
__global__ void k2r(const float* __restrict__ pm, const float* __restrict__ ps,
                    float* __restrict__ cvec) {
    int row = blockIdx.x * 256 + threadIdx.x;
    float M = MASK_NEG, S = 0.f;
#pragma unroll
    for (int i = 0; i < 8; ++i) {
        float m = pm[(size_t)i * NN + row];
        float s = ps[(size_t)i * NN + row];
        float mn = fmaxf(M, m);
        S = S * __expf(M - mn) + s * __expf(m - mn);
        M = mn;
    }
    cvec[row] = M + __logf(S);  // out = exp(v - C)
}

// ---------------- K2b: recompute e, write softmax ---------------------------
// same geometry and sync skeleton as k2a; writes out (256 MB, nontemporal)
__global__ __launch_bounds__(256, 4) void k2b(const f16* __restrict__ h,
                                              const u32* __restrict__ maskbits,
                                              const float* __restrict__ cvec,
                                              float* __restrict__ out) {
    __shared__ __align__(16) char hbuf[32768];
    int tid = threadIdx.x;
    int wave = tid >> 6, lane = tid & 63, l15 = lane & 15, lg = lane >> 4;
    int bid = blockIdx.x;
    int rb = bid >> 3, split = bid & 7;
    int rowBase = rb * 64;
    int c0 = split * 1024;

    f16x8 A[8];
    {
        const f16* ap = h + (size_t)(rowBase + wave * 16 + l15) * FF + lg * 8;
#pragma unroll
        for (int kk = 0; kk < 8; ++kk) A[kk] = *(const f16x8*)(ap + kk * 32);
    }
    float Cv[4];
#pragma unroll
    for (int r = 0; r < 4; ++r)
        Cv[r] = cvec[rowBase + wave * 16 + 4 * lg + r];

    int prow = rowBase + wave * 16 + (lane >> 2);
    int pw = (lane >> 1) & 1;

#pragma unroll 1
    for (int t = 0; t < 16; ++t) {
        __syncthreads();
        {
            const char* hb = (const char*)h + (size_t)(c0 + t * 64) * 512;
#pragma unroll
            for (int i = 0; i < 8; ++i) {
                int sb = i * 256 + wave * 64;
                int c = i * 8 + wave * 2 + (lane >> 5);
                gload_lds16(hb + (size_t)c * 512 + (((lane & 31) ^ (c & 31)) << 4),
                            hbuf + (size_t)sb * 16);
            }
        }
        // lane 4*wr+2*w(+1) loads word (row wr, word w) -- same distribution
        // as k2a's post-pack state; L2-resident, drains with the barrier
        u32 word = maskbits[(size_t)(split * 32 + t * 2 + pw) * NN + prow];
        __syncthreads();

        f32x4 acc0 = {0.f, 0.f, 0.f, 0.f}, acc1 = {0.f, 0.f, 0.f, 0.f};
        f32x4 acc2 = {0.f, 0.f, 0.f, 0.f}, acc3 = {0.f, 0.f, 0.f, 0.f};
#pragma unroll
        for (int kk = 0; kk < 8; ++kk) {
            int ks = kk * 4 + lg;
            f16x8 b0 = *(const f16x8*)(hbuf + (size_t)l15 * 512
                                       + ((ks ^ l15) << 4));
            f16x8 b1 = *(const f16x8*)(hbuf + (size_t)(16 + l15) * 512
                                       + ((ks ^ (16 + l15)) << 4));
            f16x8 b2 = *(const f16x8*)(hbuf + (size_t)(32 + l15) * 512
                                       + ((ks ^ l15) << 4));
            f16x8 b3 = *(const f16x8*)(hbuf + (size_t)(48 + l15) * 512
                                       + ((ks ^ (16 + l15)) << 4));
            acc0 = __builtin_amdgcn_mfma_f32_16x16x32_f16(A[kk], b0, acc0, 0, 0, 0);
            acc1 = __builtin_amdgcn_mfma_f32_16x16x32_f16(A[kk], b1, acc1, 0, 0, 0);
            acc2 = __builtin_amdgcn_mfma_f32_16x16x32_f16(A[kk], b2, acc2, 0, 0, 0);
            acc3 = __builtin_amdgcn_mfma_f32_16x16x32_f16(A[kk], b3, acc3, 0, 0, 0);
        }

#pragma unroll
        for (int r = 0; r < 4; ++r) {
            int R = 4 * lg + r;
            u32 wA = (u32)__shfl((int)word, 4 * R, 64);
            u32 wB = (u32)__shfl((int)word, 4 * R + 2, 64);
            float v0 = ((wA >> l15) & 1u) ? acc0[r] : MASK_NEG;
            float v1 = ((wA >> (16 + l15)) & 1u) ? acc1[r] : MASK_NEG;
            float v2 = ((wB >> l15) & 1u) ? acc2[r] : MASK_NEG;
            float v3 = ((wB >> (16 + l15)) & 1u) ? acc3[r] : MASK_NEG;
            // masked: exp(-1e30 - C) underflows to exactly 0 (matches jax)
            size_t o = (size_t)(rowBase + wave * 16 + R) * NN + c0 + t * 64 + l15;
            __builtin_nontemporal_store(__expf(v0 - Cv[r]), out + o);
            __builtin_nontemporal_store(__expf(v1 - Cv[r]), out + o + 16);
            __builtin_nontemporal_store(__expf(v2 - Cv[r]), out + o + 32);
            __builtin_nontemporal_store(__expf(v3 - Cv[r]), out + o + 48);
        }
    }
}

extern "C" void kernel_launch(void* const* d_in, const int* in_sizes, int n_in,
                              void* d_out, int out_size, void* d_ws, size_t ws_size,
                              hipStream_t stream) {
    const float* x   = (const float*)d_in[0];
    const int*   adj = (const int*)d_in[1];
    const float* w   = (const float*)d_in[2];
    float* out = (float*)d_out;
    char* ws = (char*)d_ws;

    // workspace layout (~13.2 MB, identical to r11)
    f16* h    = (f16*)(ws);                                 // 4,194,304 B
    f16* wt   = (f16*)(ws + 4194304);                       //   131,072 B
    u32* mask = (u32*)(ws + 4194304 + 131072);              // 8,388,608 B
    float* pm = (float*)(ws + 4194304 + 131072 + 8388608);  // 8*NN f32
    float* ps = pm + 8 * NN;                                // 8*NN f32
    float* cv = ps + 8 * NN;                                // NN f32

    k0_wt<<<dim3(256), dim3(256), 0, stream>>>(w, wt);
    k1_h <<<dim3(256), dim3(256), 0, stream>>>(x, wt, h);
    k2a  <<<dim3(1024), dim3(256), 0, stream>>>(h, adj, mask, pm, ps);
    k2r  <<<dim3(32),  dim3(256), 0, stream>>>(pm, ps, cv);
    k2b  <<<dim3(1024), dim3(256), 0, stream>>>(h, mask, cv, out);
}